// Round 1
// baseline (874.251 us; speedup 1.0000x reference)
//
#include <hip/hip_runtime.h>

// ---------------- CSR build ----------------

__global__ __launch_bounds__(256) void count_kernel(const int* __restrict__ col,
                                                    int* __restrict__ cnt, int E) {
    int e = blockIdx.x * 256 + threadIdx.x;
    if (e < E) atomicAdd(&cnt[col[e]], 1);
}

// Single-block exclusive scan: 1024 threads, each owns a contiguous chunk.
__global__ __launch_bounds__(1024) void scan_kernel(const int* __restrict__ cnt,
                                                    int* __restrict__ off, int n) {
    const int tid = threadIdx.x;
    const int per = (n + 1023) >> 10;
    const int s0 = tid * per;
    const int s1 = min(s0 + per, n);
    int sum = 0;
    for (int i = s0; i < s1; ++i) sum += cnt[i];
    const int lane = tid & 63, w = tid >> 6;
    int x = sum;
#pragma unroll
    for (int d = 1; d < 64; d <<= 1) {
        int t = __shfl_up(x, d);
        if (lane >= d) x += t;
    }
    __shared__ int wtot[16], wbase[16];
    if (lane == 63) wtot[w] = x;
    __syncthreads();
    if (tid == 0) {
        int acc = 0;
        for (int i = 0; i < 16; ++i) { int t = wtot[i]; wbase[i] = acc; acc += t; }
    }
    __syncthreads();
    int run = wbase[w] + x - sum;   // exclusive prefix for this thread's chunk
    for (int i = s0; i < s1; ++i) { off[i] = run; run += cnt[i]; }
    if (tid == 1023) off[n] = run;  // total = E
}

__global__ __launch_bounds__(256) void dinv_kernel(const int* __restrict__ cnt,
                                                   float* __restrict__ dinv, int n) {
    int i = blockIdx.x * 256 + threadIdx.x;
    if (i < n) {
        int c = cnt[i];
        dinv[i] = (c > 0) ? 1.0f / sqrtf((float)c) : 0.0f;
    }
}

__global__ __launch_bounds__(256) void scatter_kernel(const int* __restrict__ row,
                                                      const int* __restrict__ col,
                                                      const int* __restrict__ off,
                                                      int* __restrict__ cursor,
                                                      const float* __restrict__ dinv,
                                                      int* __restrict__ srcs,
                                                      float* __restrict__ norms, int E) {
    int e = blockIdx.x * 256 + threadIdx.x;
    if (e >= E) return;
    int r = row[e], c = col[e];
    int pos = off[c] + atomicAdd(&cursor[c], 1);
    srcs[pos] = r;
    norms[pos] = dinv[r] * dinv[c];
}

// ---------------- propagation: out_i = sum_{e: col=i} norm_e * h[row_e] ----------------
// DQ = feature_dim / 4 lanes per node, each lane owns one float4 of the row.

template <int DQ>
__global__ __launch_bounds__(256) void prop_kernel(const int* __restrict__ off,
                                                   const int* __restrict__ srcs,
                                                   const float* __restrict__ norms,
                                                   const float* __restrict__ hin,
                                                   float* __restrict__ hout, int nNodes) {
    int t = blockIdx.x * 256 + threadIdx.x;
    int n = t / DQ;
    int q = t & (DQ - 1);
    if (n >= nNodes) return;
    const float4* __restrict__ h4 = (const float4*)hin;
    float4 acc = make_float4(0.f, 0.f, 0.f, 0.f);
    const int e1 = off[n + 1];
    for (int e = off[n]; e < e1; ++e) {
        const int s = srcs[e];
        const float ww = norms[e];
        float4 hv = h4[s * DQ + q];
        acc.x += ww * hv.x;
        acc.y += ww * hv.y;
        acc.z += ww * hv.z;
        acc.w += ww * hv.w;
    }
    ((float4*)hout)[n * DQ + q] = acc;
}

// ---------------- dense: out[n][:] (+)= h[n][:] @ W (+b) ----------------
// DOUT=64 variant: 16 lanes/node, each computes 4 outputs.

template <int DIN, bool INIT, bool RELU>
__global__ __launch_bounds__(256) void gemm64_kernel(const float* __restrict__ h,
                                                     const float* __restrict__ W,
                                                     const float* __restrict__ b,
                                                     float* __restrict__ out, int nNodes) {
    __shared__ float Ws[DIN * 64];
    __shared__ float bs[64];
    for (int i = threadIdx.x; i < DIN * 64; i += 256) Ws[i] = W[i];
    if (threadIdx.x < 64) bs[threadIdx.x] = b[threadIdx.x];
    __syncthreads();
    const int q = threadIdx.x & 15;
    const int n = blockIdx.x * 16 + (threadIdx.x >> 4);
    if (n >= nNodes) return;
    const float4* __restrict__ h4 = (const float4*)(h + n * DIN);
    float4* o = (float4*)(out + n * 64) + q;
    float4 acc;
    if (INIT)
        acc = make_float4(bs[q * 4 + 0], bs[q * 4 + 1], bs[q * 4 + 2], bs[q * 4 + 3]);
    else
        acc = *o;
    const float4* W4 = (const float4*)Ws;
#pragma unroll
    for (int i4 = 0; i4 < DIN / 4; ++i4) {
        float4 hv = h4[i4];
        float4 w0 = W4[(i4 * 4 + 0) * 16 + q];
        float4 w1 = W4[(i4 * 4 + 1) * 16 + q];
        float4 w2 = W4[(i4 * 4 + 2) * 16 + q];
        float4 w3 = W4[(i4 * 4 + 3) * 16 + q];
        acc.x += hv.x * w0.x + hv.y * w1.x + hv.z * w2.x + hv.w * w3.x;
        acc.y += hv.x * w0.y + hv.y * w1.y + hv.z * w2.y + hv.w * w3.y;
        acc.z += hv.x * w0.z + hv.y * w1.z + hv.z * w2.z + hv.w * w3.z;
        acc.w += hv.x * w0.w + hv.y * w1.w + hv.z * w2.w + hv.w * w3.w;
    }
    if (RELU) {
        acc.x = fmaxf(acc.x, 0.f);
        acc.y = fmaxf(acc.y, 0.f);
        acc.z = fmaxf(acc.z, 0.f);
        acc.w = fmaxf(acc.w, 0.f);
    }
    *o = acc;
}

// DOUT=4 variant (final layer): 4 lanes/node, each computes 1 output.
template <bool INIT>
__global__ __launch_bounds__(256) void gemm4_kernel(const float* __restrict__ h,
                                                    const float* __restrict__ W,
                                                    const float* __restrict__ b,
                                                    float* __restrict__ out, int nNodes) {
    __shared__ float Ws[64 * 4];
    __shared__ float bs[4];
    if (threadIdx.x < 256) Ws[threadIdx.x] = W[threadIdx.x];
    if (threadIdx.x < 4) bs[threadIdx.x] = b[threadIdx.x];
    __syncthreads();
    const int q = threadIdx.x & 3;
    const int n = blockIdx.x * 64 + (threadIdx.x >> 2);
    if (n >= nNodes) return;
    const float4* __restrict__ h4 = (const float4*)(h + n * 64);
    float acc = INIT ? bs[q] : out[n * 4 + q];
#pragma unroll
    for (int i4 = 0; i4 < 16; ++i4) {
        float4 hv = h4[i4];
        acc += hv.x * Ws[(i4 * 4 + 0) * 4 + q] + hv.y * Ws[(i4 * 4 + 1) * 4 + q] +
               hv.z * Ws[(i4 * 4 + 2) * 4 + q] + hv.w * Ws[(i4 * 4 + 3) * 4 + q];
    }
    out[n * 4 + q] = acc;
}

// ---------------- host ----------------

extern "C" void kernel_launch(void* const* d_in, const int* in_sizes, int n_in,
                              void* d_out, int out_size, void* d_ws, size_t ws_size,
                              hipStream_t stream) {
    const float* x = (const float*)d_in[0];
    const int* ei = (const int*)d_in[1];  // [2][E] int32: row=ei[e], col=ei[E+e]
    const float* W[5] = {(const float*)d_in[2], (const float*)d_in[4], (const float*)d_in[6],
                         (const float*)d_in[8], (const float*)d_in[10]};
    const float* bb[5] = {(const float*)d_in[3], (const float*)d_in[5], (const float*)d_in[7],
                          (const float*)d_in[9], (const float*)d_in[11]};
    const int E = in_sizes[1] / 2;   // 800000
    const int N = in_sizes[0] / 16;  // 50000
    float* outp = (float*)d_out;

    char* p = (char*)d_ws;
    auto alloc = [&](size_t bytes) {
        char* r = p;
        p += (bytes + 255) & ~size_t(255);
        return r;
    };
    int* cnt = (int*)alloc((size_t)N * 4);
    int* off = (int*)alloc((size_t)(N + 1) * 4);
    int* cursor = (int*)alloc((size_t)N * 4);
    float* dinv = (float*)alloc((size_t)N * 4);
    int* srcs = (int*)alloc((size_t)E * 4);
    float* norms = (float*)alloc((size_t)E * 4);
    float* A = (float*)alloc((size_t)N * 64 * 4);
    float* B = (float*)alloc((size_t)N * 64 * 4);
    float* C = (float*)alloc((size_t)N * 64 * 4);
    float* O = (float*)alloc((size_t)N * 64 * 4);

    hipMemsetAsync(cnt, 0, (size_t)N * 4, stream);
    hipMemsetAsync(cursor, 0, (size_t)N * 4, stream);
    const int eb = (E + 255) / 256;
    const int nb = (N + 255) / 256;
    count_kernel<<<eb, 256, 0, stream>>>(ei + E, cnt, E);
    scan_kernel<<<1, 1024, 0, stream>>>(cnt, off, N);
    dinv_kernel<<<nb, 256, 0, stream>>>(cnt, dinv, N);
    scatter_kernel<<<eb, 256, 0, stream>>>(ei, ei + E, off, cursor, dinv, srcs, norms, E);

    const int g64 = (N + 15) / 16;
    const int g4 = (N + 63) / 64;
    const int p16 = (N * 16 + 255) / 256;
    const int p4 = (N * 4 + 255) / 256;

    // Layer 0: x(16) -> O  (hops are 16-dim)
    gemm64_kernel<16, true, false><<<g64, 256, 0, stream>>>(x, W[0] + 0 * 16 * 64, bb[0], O, N);
    prop_kernel<4><<<p4, 256, 0, stream>>>(off, srcs, norms, x, B, N);
    gemm64_kernel<16, false, false><<<g64, 256, 0, stream>>>(B, W[0] + 1 * 16 * 64, bb[0], O, N);
    prop_kernel<4><<<p4, 256, 0, stream>>>(off, srcs, norms, B, C, N);
    gemm64_kernel<16, false, false><<<g64, 256, 0, stream>>>(C, W[0] + 2 * 16 * 64, bb[0], O, N);
    prop_kernel<4><<<p4, 256, 0, stream>>>(off, srcs, norms, C, B, N);
    gemm64_kernel<16, false, true><<<g64, 256, 0, stream>>>(B, W[0] + 3 * 16 * 64, bb[0], O, N);

    // Layers 1-3: 64 -> 64, ping-pong cur/nxt between O and A
    float* cur = O;
    float* nxt = A;
    for (int l = 1; l <= 3; ++l) {
        const float* Wl = W[l];
        const float* bl = bb[l];
        gemm64_kernel<64, true, false><<<g64, 256, 0, stream>>>(cur, Wl + 0 * 4096, bl, nxt, N);
        prop_kernel<16><<<p16, 256, 0, stream>>>(off, srcs, norms, cur, B, N);
        gemm64_kernel<64, false, false><<<g64, 256, 0, stream>>>(B, Wl + 1 * 4096, bl, nxt, N);
        prop_kernel<16><<<p16, 256, 0, stream>>>(off, srcs, norms, B, C, N);
        gemm64_kernel<64, false, false><<<g64, 256, 0, stream>>>(C, Wl + 2 * 4096, bl, nxt, N);
        prop_kernel<16><<<p16, 256, 0, stream>>>(off, srcs, norms, C, B, N);
        gemm64_kernel<64, false, true><<<g64, 256, 0, stream>>>(B, Wl + 3 * 4096, bl, nxt, N);
        float* t = cur;
        cur = nxt;
        nxt = t;
    }

    // Layer 4: cur(64) -> d_out(4), no relu
    gemm4_kernel<true><<<g4, 256, 0, stream>>>(cur, W[4] + 0 * 256, bb[4], outp, N);
    prop_kernel<16><<<p16, 256, 0, stream>>>(off, srcs, norms, cur, B, N);
    gemm4_kernel<false><<<g4, 256, 0, stream>>>(B, W[4] + 1 * 256, bb[4], outp, N);
    prop_kernel<16><<<p16, 256, 0, stream>>>(off, srcs, norms, B, C, N);
    gemm4_kernel<false><<<g4, 256, 0, stream>>>(C, W[4] + 2 * 256, bb[4], outp, N);
    prop_kernel<16><<<p16, 256, 0, stream>>>(off, srcs, norms, C, B, N);
    gemm4_kernel<false><<<g4, 256, 0, stream>>>(B, W[4] + 3 * 256, bb[4], outp, N);
}

// Round 2
// 629.613 us; speedup vs baseline: 1.3886x; 1.3886x over previous
//
#include <hip/hip_runtime.h>

// ---------------- CSR build ----------------

__global__ __launch_bounds__(256) void count_kernel(const int* __restrict__ col,
                                                    int* __restrict__ cnt, int E) {
    int e = blockIdx.x * 256 + threadIdx.x;
    if (e < E) atomicAdd(&cnt[col[e]], 1);
}

// Hierarchical scan, stage 1: per-block exclusive scan + block totals.
__global__ __launch_bounds__(256) void scan_block_kernel(const int* __restrict__ cnt,
                                                         int* __restrict__ off,
                                                         int* __restrict__ bsum, int n) {
    const int gid = blockIdx.x * 256 + threadIdx.x;
    const int v = (gid < n) ? cnt[gid] : 0;
    const int lane = threadIdx.x & 63, w = threadIdx.x >> 6;
    int x = v;
#pragma unroll
    for (int d = 1; d < 64; d <<= 1) {
        int t = __shfl_up(x, d);
        if (lane >= d) x += t;
    }
    __shared__ int wt[4];
    if (lane == 63) wt[w] = x;
    __syncthreads();
    int base = 0;
#pragma unroll
    for (int i = 0; i < 3; ++i)
        if (i < w) base += wt[i];
    const int incl = base + x;
    if (gid < n) off[gid] = incl - v;  // block-local exclusive
    if (threadIdx.x == 255) bsum[blockIdx.x] = incl;
}

// Stage 2: exclusive scan of block sums (nb <= 256) in one block.
__global__ __launch_bounds__(256) void scan_bsum_kernel(const int* __restrict__ bsum,
                                                        int* __restrict__ bbase, int nb) {
    const int tid = threadIdx.x;
    const int v = (tid < nb) ? bsum[tid] : 0;
    const int lane = tid & 63, w = tid >> 6;
    int x = v;
#pragma unroll
    for (int d = 1; d < 64; d <<= 1) {
        int t = __shfl_up(x, d);
        if (lane >= d) x += t;
    }
    __shared__ int wt[4];
    if (lane == 63) wt[w] = x;
    __syncthreads();
    int base = 0;
#pragma unroll
    for (int i = 0; i < 3; ++i)
        if (i < w) base += wt[i];
    if (tid < nb) bbase[tid] = base + x - v;
}

// Stage 3: add block bases; set off[n] = E.
__global__ __launch_bounds__(256) void scan_apply_kernel(int* __restrict__ off,
                                                         const int* __restrict__ bbase,
                                                         int n, int E) {
    const int gid = blockIdx.x * 256 + threadIdx.x;
    if (gid < n) off[gid] += bbase[blockIdx.x];
    if (gid == n) off[n] = E;
}

__global__ __launch_bounds__(256) void dinv_kernel(const int* __restrict__ cnt,
                                                   float* __restrict__ dinv, int n) {
    int i = blockIdx.x * 256 + threadIdx.x;
    if (i < n) {
        int c = cnt[i];
        dinv[i] = (c > 0) ? 1.0f / sqrtf((float)c) : 0.0f;
    }
}

__global__ __launch_bounds__(256) void scatter_kernel(const int* __restrict__ row,
                                                      const int* __restrict__ col,
                                                      const int* __restrict__ off,
                                                      int* __restrict__ cursor,
                                                      const float* __restrict__ dinv,
                                                      int2* __restrict__ recs, int E) {
    int e = blockIdx.x * 256 + threadIdx.x;
    if (e >= E) return;
    int r = row[e], c = col[e];
    int pos = off[c] + atomicAdd(&cursor[c], 1);
    recs[pos] = make_int2(r, __float_as_int(dinv[r] * dinv[c]));
}

// ---------------- propagation: out_i = sum_{e: col=i} norm_e * h[row_e] ----------------
// DQ = feature_dim/4 lanes per node; each lane owns one float4 of the row.
// Edge records packed (src, norm); edge loop 4x unrolled for MLP.

template <int DQ>
__global__ __launch_bounds__(256) void prop_kernel(const int* __restrict__ off,
                                                   const int2* __restrict__ recs,
                                                   const float* __restrict__ hin,
                                                   float* __restrict__ hout, int nNodes) {
    const int t = blockIdx.x * 256 + threadIdx.x;
    const int n = (DQ == 1) ? t : t / DQ;
    const int q = (DQ == 1) ? 0 : (t & (DQ - 1));
    if (n >= nNodes) return;
    const float4* __restrict__ h4 = (const float4*)hin;
    float4 acc = make_float4(0.f, 0.f, 0.f, 0.f);
    int e = off[n];
    const int e1 = off[n + 1];
    for (; e + 4 <= e1; e += 4) {
        const int2 r0 = recs[e + 0];
        const int2 r1 = recs[e + 1];
        const int2 r2 = recs[e + 2];
        const int2 r3 = recs[e + 3];
        const float4 a = h4[r0.x * DQ + q];
        const float4 b = h4[r1.x * DQ + q];
        const float4 c = h4[r2.x * DQ + q];
        const float4 d = h4[r3.x * DQ + q];
        const float w0 = __int_as_float(r0.y), w1 = __int_as_float(r1.y);
        const float w2 = __int_as_float(r2.y), w3 = __int_as_float(r3.y);
        acc.x += w0 * a.x + w1 * b.x + w2 * c.x + w3 * d.x;
        acc.y += w0 * a.y + w1 * b.y + w2 * c.y + w3 * d.y;
        acc.z += w0 * a.z + w1 * b.z + w2 * c.z + w3 * d.z;
        acc.w += w0 * a.w + w1 * b.w + w2 * c.w + w3 * d.w;
    }
    for (; e < e1; ++e) {
        const int2 r = recs[e];
        const float4 hv = h4[r.x * DQ + q];
        const float ww = __int_as_float(r.y);
        acc.x += ww * hv.x;
        acc.y += ww * hv.y;
        acc.z += ww * hv.z;
        acc.w += ww * hv.w;
    }
    ((float4*)hout)[n * DQ + q] = acc;
}

// ---------------- dense: out[n][:] (+)= h[n][:] @ W (+b) ----------------
// DOUT=64 variant: 16 lanes/node, each computes 4 outputs.

template <int DIN, bool INIT, bool RELU>
__global__ __launch_bounds__(256) void gemm64_kernel(const float* __restrict__ h,
                                                     const float* __restrict__ W,
                                                     const float* __restrict__ b,
                                                     float* __restrict__ out, int nNodes) {
    __shared__ float Ws[DIN * 64];
    __shared__ float bs[64];
    for (int i = threadIdx.x; i < DIN * 64; i += 256) Ws[i] = W[i];
    if (threadIdx.x < 64) bs[threadIdx.x] = b[threadIdx.x];
    __syncthreads();
    const int q = threadIdx.x & 15;
    const int n = blockIdx.x * 16 + (threadIdx.x >> 4);
    if (n >= nNodes) return;
    const float4* __restrict__ h4 = (const float4*)(h + n * DIN);
    float4* o = (float4*)(out + n * 64) + q;
    float4 acc;
    if (INIT)
        acc = make_float4(bs[q * 4 + 0], bs[q * 4 + 1], bs[q * 4 + 2], bs[q * 4 + 3]);
    else
        acc = *o;
    const float4* W4 = (const float4*)Ws;
#pragma unroll
    for (int i4 = 0; i4 < DIN / 4; ++i4) {
        float4 hv = h4[i4];
        float4 w0 = W4[(i4 * 4 + 0) * 16 + q];
        float4 w1 = W4[(i4 * 4 + 1) * 16 + q];
        float4 w2 = W4[(i4 * 4 + 2) * 16 + q];
        float4 w3 = W4[(i4 * 4 + 3) * 16 + q];
        acc.x += hv.x * w0.x + hv.y * w1.x + hv.z * w2.x + hv.w * w3.x;
        acc.y += hv.x * w0.y + hv.y * w1.y + hv.z * w2.y + hv.w * w3.y;
        acc.z += hv.x * w0.z + hv.y * w1.z + hv.z * w2.z + hv.w * w3.z;
        acc.w += hv.x * w0.w + hv.y * w1.w + hv.z * w2.w + hv.w * w3.w;
    }
    if (RELU) {
        acc.x = fmaxf(acc.x, 0.f);
        acc.y = fmaxf(acc.y, 0.f);
        acc.z = fmaxf(acc.z, 0.f);
        acc.w = fmaxf(acc.w, 0.f);
    }
    *o = acc;
}

// DOUT=4 variant (final layer). MODE: 0 = out = h@W; 1 = out += h@W;
// 2 = out = h@W + b + add (final combine).
template <int MODE>
__global__ __launch_bounds__(256) void gemm4_kernel(const float* __restrict__ h,
                                                    const float* __restrict__ W,
                                                    const float* __restrict__ b,
                                                    const float* __restrict__ add,
                                                    float* __restrict__ out, int nNodes) {
    __shared__ float Ws[64 * 4];
    __shared__ float bs[4];
    if (threadIdx.x < 256) Ws[threadIdx.x] = W[threadIdx.x];
    if (MODE == 2 && threadIdx.x < 4) bs[threadIdx.x] = b[threadIdx.x];
    __syncthreads();
    const int q = threadIdx.x & 3;
    const int n = blockIdx.x * 64 + (threadIdx.x >> 2);
    if (n >= nNodes) return;
    const float4* __restrict__ h4 = (const float4*)(h + n * 64);
    float acc = 0.f;
#pragma unroll
    for (int i4 = 0; i4 < 16; ++i4) {
        float4 hv = h4[i4];
        acc += hv.x * Ws[(i4 * 4 + 0) * 4 + q] + hv.y * Ws[(i4 * 4 + 1) * 4 + q] +
               hv.z * Ws[(i4 * 4 + 2) * 4 + q] + hv.w * Ws[(i4 * 4 + 3) * 4 + q];
    }
    const int idx = n * 4 + q;
    if (MODE == 0)
        out[idx] = acc;
    else if (MODE == 1)
        out[idx] += acc;
    else
        out[idx] = acc + bs[q] + add[idx];
}

// ---------------- host ----------------

extern "C" void kernel_launch(void* const* d_in, const int* in_sizes, int n_in,
                              void* d_out, int out_size, void* d_ws, size_t ws_size,
                              hipStream_t stream) {
    const float* x = (const float*)d_in[0];
    const int* ei = (const int*)d_in[1];  // [2][E]: row=ei[e], col=ei[E+e]
    const float* W[5] = {(const float*)d_in[2], (const float*)d_in[4], (const float*)d_in[6],
                         (const float*)d_in[8], (const float*)d_in[10]};
    const float* bb[5] = {(const float*)d_in[3], (const float*)d_in[5], (const float*)d_in[7],
                          (const float*)d_in[9], (const float*)d_in[11]};
    const int E = in_sizes[1] / 2;   // 800000
    const int N = in_sizes[0] / 16;  // 50000
    float* outp = (float*)d_out;

    char* p = (char*)d_ws;
    auto alloc = [&](size_t bytes) {
        char* r = p;
        p += (bytes + 255) & ~size_t(255);
        return r;
    };
    const int nb = (N + 255) / 256;  // 196
    int* cnt = (int*)alloc((size_t)N * 4);
    int* off = (int*)alloc((size_t)(N + 1) * 4);
    int* cursor = (int*)alloc((size_t)N * 4);
    float* dinv = (float*)alloc((size_t)N * 4);
    int* bsum = (int*)alloc((size_t)nb * 4);
    int* bbase = (int*)alloc((size_t)nb * 4);
    int2* recs = (int2*)alloc((size_t)E * 8);
    float* A = (float*)alloc((size_t)N * 64 * 4);
    float* B = (float*)alloc((size_t)N * 64 * 4);
    float* C = (float*)alloc((size_t)N * 64 * 4);
    float* O = (float*)alloc((size_t)N * 64 * 4);
    float* T1 = (float*)alloc((size_t)N * 4 * 4);
    float* T2 = (float*)alloc((size_t)N * 4 * 4);

    hipMemsetAsync(cnt, 0, (size_t)N * 4, stream);
    hipMemsetAsync(cursor, 0, (size_t)N * 4, stream);
    const int eb = (E + 255) / 256;
    count_kernel<<<eb, 256, 0, stream>>>(ei + E, cnt, E);
    scan_block_kernel<<<nb, 256, 0, stream>>>(cnt, off, bsum, N);
    scan_bsum_kernel<<<1, 256, 0, stream>>>(bsum, bbase, nb);
    scan_apply_kernel<<<nb, 256, 0, stream>>>(off, bbase, N, E);
    dinv_kernel<<<nb, 256, 0, stream>>>(cnt, dinv, N);
    scatter_kernel<<<eb, 256, 0, stream>>>(ei, ei + E, off, cursor, dinv, recs, E);

    const int g64 = (N + 15) / 16;
    const int g4 = (N + 63) / 64;
    const int p16 = (N * 16 + 255) / 256;
    const int p4 = (N * 4 + 255) / 256;
    const int p1 = (N + 255) / 256;

    // Layer 0: x(16) -> O  (hops on 16-dim x)
    gemm64_kernel<16, true, false><<<g64, 256, 0, stream>>>(x, W[0] + 0 * 1024, bb[0], O, N);
    prop_kernel<4><<<p4, 256, 0, stream>>>(off, recs, x, B, N);
    gemm64_kernel<16, false, false><<<g64, 256, 0, stream>>>(B, W[0] + 1 * 1024, bb[0], O, N);
    prop_kernel<4><<<p4, 256, 0, stream>>>(off, recs, B, C, N);
    gemm64_kernel<16, false, false><<<g64, 256, 0, stream>>>(C, W[0] + 2 * 1024, bb[0], O, N);
    prop_kernel<4><<<p4, 256, 0, stream>>>(off, recs, C, B, N);
    gemm64_kernel<16, false, true><<<g64, 256, 0, stream>>>(B, W[0] + 3 * 1024, bb[0], O, N);

    // Layers 1-3: 64 -> 64, ping-pong cur/nxt between O and A
    float* cur = O;
    float* nxt = A;
    for (int l = 1; l <= 3; ++l) {
        const float* Wl = W[l];
        const float* bl = bb[l];
        gemm64_kernel<64, true, false><<<g64, 256, 0, stream>>>(cur, Wl + 0 * 4096, bl, nxt, N);
        prop_kernel<16><<<p16, 256, 0, stream>>>(off, recs, cur, B, N);
        gemm64_kernel<64, false, false><<<g64, 256, 0, stream>>>(B, Wl + 1 * 4096, bl, nxt, N);
        prop_kernel<16><<<p16, 256, 0, stream>>>(off, recs, B, C, N);
        gemm64_kernel<64, false, false><<<g64, 256, 0, stream>>>(C, Wl + 2 * 4096, bl, nxt, N);
        prop_kernel<16><<<p16, 256, 0, stream>>>(off, recs, C, B, N);
        gemm64_kernel<64, false, true><<<g64, 256, 0, stream>>>(B, Wl + 3 * 4096, bl, nxt, N);
        float* t = cur;
        cur = nxt;
        nxt = t;
    }

    // Layer 4 via Horner on the FEATURE-PROJECTED (4-dim) signal:
    // out = cur@W0 + A(cur@W1 + A(cur@W2 + A(cur@W3))) + b
    gemm4_kernel<0><<<g4, 256, 0, stream>>>(cur, W[4] + 3 * 256, nullptr, nullptr, T1, N);
    prop_kernel<1><<<p1, 256, 0, stream>>>(off, recs, T1, T2, N);
    gemm4_kernel<1><<<g4, 256, 0, stream>>>(cur, W[4] + 2 * 256, nullptr, nullptr, T2, N);
    prop_kernel<1><<<p1, 256, 0, stream>>>(off, recs, T2, T1, N);
    gemm4_kernel<1><<<g4, 256, 0, stream>>>(cur, W[4] + 1 * 256, nullptr, nullptr, T1, N);
    prop_kernel<1><<<p1, 256, 0, stream>>>(off, recs, T1, T2, N);
    gemm4_kernel<2><<<g4, 256, 0, stream>>>(cur, W[4] + 0 * 256, bb[4], T2, outp, N);
}